// Round 13
// baseline (342.038 us; speedup 1.0000x reference)
//
#include <hip/hip_runtime.h>
#include <hip/hip_bf16.h>
#include <cstdint>
#include <cstddef>

#define D 128
#define SCAN_CHUNK 1024
#define NBK 1024   // coarse buckets (dst >> 7); supports n <= 131072
#define PBLK 128   // blocks for coarse hist/scatter

typedef __attribute__((ext_vector_type(8))) __bf16 bf16v8;
typedef __attribute__((ext_vector_type(4))) float f32v4;

// Round-to-nearest-even fp32 -> bf16 (bits), packed pair.
__device__ inline unsigned int pack_bf16x2(float a, float b) {
  unsigned int ua = __float_as_uint(a);
  unsigned int ub = __float_as_uint(b);
  ua = (ua + 0x7fffu + ((ua >> 16) & 1u)) >> 16;
  ub = (ub + 0x7fffu + ((ub >> 16) & 1u)) >> 16;
  return ua | (ub << 16);
}
__device__ inline float bf_lo(unsigned int u) { return __uint_as_float(u << 16); }
__device__ inline float bf_hi(unsigned int u) { return __uint_as_float(u & 0xffff0000u); }

// ---------------------------------------------------------------------------
// Two-level counting sort with ZERO device-scope atomics (round 13).
// Evidence (R5/R6/R11/R12): hist/scatter stuck at ~40us each regardless of
// ILP, occupancy, or counter padding -> far-atomic op throughput (~6.7/cy
// chip-wide past the non-coherent XCD L2s) is the wall.  All atomics below
// are LDS-scope.  Final `sorted` format identical to before: rows padded to
// multiple of 8 with (0,0.0f); records (src<<8, val); rowptr[N+1] deltas are
// padded lengths.
// ---------------------------------------------------------------------------

// Coarse histogram: LDS 1024-bucket hist per block, coalesced flush.
__global__ __launch_bounds__(256) void coarse_hist(
    const int* __restrict__ dst, int* __restrict__ Hc, int E, int chunk) {
  __shared__ int h[NBK];
  for (int i = threadIdx.x; i < NBK; i += 256) h[i] = 0;
  __syncthreads();
  int s = blockIdx.x * chunk;
  int e = s + chunk; if (e > E) e = E;
  for (int i = s + threadIdx.x; i < e; i += 256)
    atomicAdd(&h[dst[i] >> 7], 1);
  __syncthreads();
  for (int i = threadIdx.x; i < NBK; i += 256)
    Hc[(size_t)blockIdx.x * NBK + i] = h[i];
}

// Bucket totals + exclusive scan -> Bbase[NBK+1].
__global__ __launch_bounds__(1024) void coarse_scan_tot(
    const int* __restrict__ Hc, int* __restrict__ Bbase, int nblk) {
  __shared__ int sdata[NBK];
  const int t = threadIdx.x;
  int s = 0;
  for (int bl = 0; bl < nblk; ++bl) s += Hc[(size_t)bl * NBK + t];
  sdata[t] = s;
  __syncthreads();
  for (int off = 1; off < NBK; off <<= 1) {
    int x = (t >= off) ? sdata[t - off] : 0;
    __syncthreads();
    sdata[t] += x;
    __syncthreads();
  }
  Bbase[t] = sdata[t] - s;  // exclusive
  if (t == NBK - 1) Bbase[NBK] = sdata[t];
}

// Convert Hc[bl][b] in place to per-(block,bucket) exclusive bases.
__global__ __launch_bounds__(256) void coarse_bases(
    int* __restrict__ Hc, const int* __restrict__ Bbase, int nblk) {
  int b = blockIdx.x * 256 + threadIdx.x;  // grid = NBK/256
  int run = Bbase[b];
  for (int bl = 0; bl < nblk; ++bl) {
    int c = Hc[(size_t)bl * NBK + b];
    Hc[(size_t)bl * NBK + b] = run;
    run += c;
  }
}

// Coarse scatter: LDS cursors (seeded from Hc bases); record packs dst low
// bits into the free low byte of src<<8 (bit 7 unused).
__global__ __launch_bounds__(256) void coarse_scatter(
    const int* __restrict__ src, const int* __restrict__ dst,
    const float* __restrict__ val, const int* __restrict__ Hc,
    int2* __restrict__ coarse, int E, int chunk) {
  __shared__ int cur[NBK];
  for (int i = threadIdx.x; i < NBK; i += 256)
    cur[i] = Hc[(size_t)blockIdx.x * NBK + i];
  __syncthreads();
  int s = blockIdx.x * chunk;
  int e = s + chunk; if (e > E) e = E;
  for (int i = s + threadIdx.x; i < e; i += 256) {
    int d = dst[i];
    int pos = atomicAdd(&cur[d >> 7], 1);   // LDS atomic
    coarse[pos] = make_int2((src[i] << 8) | (d & 127), __float_as_int(val[i]));
  }
}

// Fine histogram per 128-row bucket -> count[] (coalesced; no memset needed).
__global__ __launch_bounds__(256) void fine_hist(
    const int2* __restrict__ coarse, const int* __restrict__ Bbase,
    int* __restrict__ count, int n) {
  __shared__ int cnt[128];
  if (threadIdx.x < 128) cnt[threadIdx.x] = 0;
  __syncthreads();
  const int b = blockIdx.x;
  const int s = Bbase[b], e = Bbase[b + 1];
  for (int i = s + threadIdx.x; i < e; i += 256)
    atomicAdd(&cnt[coarse[i].x & 127], 1);  // LDS atomic
  __syncthreads();
  int r = b * 128 + threadIdx.x;
  if (threadIdx.x < 128 && r < n) count[r] = cnt[threadIdx.x];
}

// Scans PADDED lengths: pad8(c) = (c+7)&~7.
__global__ __launch_bounds__(256) void scan_blocks(
    const int* __restrict__ count, int* __restrict__ rowptr,
    int* __restrict__ blockSums, int n) {
  __shared__ int sdata[256];
  const int tid = threadIdx.x;
  const int base = blockIdx.x * SCAN_CHUNK;
  int v[4];
#pragma unroll
  for (int k = 0; k < 4; ++k) {
    int idx = base + tid * 4 + k;
    int c = (idx < n) ? count[idx] : 0;
    v[k] = (c + 7) & ~7;
  }
  int s = v[0] + v[1] + v[2] + v[3];
  sdata[tid] = s;
  __syncthreads();
  for (int off = 1; off < 256; off <<= 1) {
    int x = (tid >= off) ? sdata[tid - off] : 0;
    __syncthreads();
    sdata[tid] += x;
    __syncthreads();
  }
  int run = sdata[tid] - s;
#pragma unroll
  for (int k = 0; k < 4; ++k) {
    int idx = base + tid * 4 + k;
    if (idx < n) rowptr[idx] = run;
    run += v[k];
  }
  if (tid == 255) blockSums[blockIdx.x] = sdata[255];
}

__global__ __launch_bounds__(256) void scan_top(int* __restrict__ bs, int nblk) {
  __shared__ int sdata[256];
  const int tid = threadIdx.x;
  int v[4];
#pragma unroll
  for (int k = 0; k < 4; ++k) {
    int idx = tid * 4 + k;
    v[k] = (idx < nblk) ? bs[idx] : 0;
  }
  int s = v[0] + v[1] + v[2] + v[3];
  sdata[tid] = s;
  __syncthreads();
  for (int off = 1; off < 256; off <<= 1) {
    int x = (tid >= off) ? sdata[tid - off] : 0;
    __syncthreads();
    sdata[tid] += x;
    __syncthreads();
  }
  int run = sdata[tid] - s;
#pragma unroll
  for (int k = 0; k < 4; ++k) {
    int idx = tid * 4 + k;
    if (idx < nblk) { int t = v[k]; bs[idx] = run; run += t; }
  }
}

// Finalize rowptr, zero-fill each row's padding slots, write terminator.
__global__ __launch_bounds__(256) void add_offsets(
    int* __restrict__ rowptr, const int* __restrict__ bs,
    const int* __restrict__ count, int2* __restrict__ sorted, int n) {
  int i = blockIdx.x * 256 + threadIdx.x;
  if (i < n) {
    int v = rowptr[i] + bs[i >> 10];
    rowptr[i] = v;
    int c = count[i];
    int lp = (c + 7) & ~7;
    for (int k = c; k < lp; ++k) sorted[v + k] = make_int2(0, 0);
    if (i == n - 1) rowptr[n] = v + lp;
  }
}

// Fine scatter: LDS cursors seeded from rowptr; final records (src<<8, val).
__global__ __launch_bounds__(256) void fine_scatter(
    const int2* __restrict__ coarse, const int* __restrict__ Bbase,
    const int* __restrict__ rowptr, int2* __restrict__ sorted, int n) {
  __shared__ int cur[128];
  const int b = blockIdx.x;
  int r = b * 128 + threadIdx.x;
  if (threadIdx.x < 128) cur[threadIdx.x] = (r < n) ? rowptr[r] : 0;
  __syncthreads();
  const int s = Bbase[b], e = Bbase[b + 1];
  for (int i = s + threadIdx.x; i < e; i += 256) {
    int2 rec = coarse[i];
    int pos = atomicAdd(&cur[rec.x & 127], 1);  // LDS atomic
    sorted[pos] = make_int2(rec.x & (int)0xFFFFFF00, rec.y);
  }
}

// ---------------------------------------------------------------------------
// Dense transform Y = in @ W^T (round-14 structure + inline W cast).
// Operand-swapped MFMA (A=W frag, B=H frag -> lane holds Y[row][4 consecutive
// cols] -> 8 x 8B uint2 stores per lane), coalesced LDS staging for H and W,
// 512-thread blocks (16 waves/CU at the 2-block LDS limit).  W is staged
// DIRECTLY from the fp32 input with in-flight bf16 conversion.
// ---------------------------------------------------------------------------
template <int F32IN>
__global__ __launch_bounds__(512) void dense_nt(
    const void* __restrict__ in_v, const float* __restrict__ Wf,
    unsigned short* __restrict__ out, int M) {
  __shared__ __align__(16) unsigned short Hs[128 * 136];
  __shared__ __align__(16) unsigned short Ws[128 * 136];

  const int tid = threadIdx.x;          // 0..511
  const int w = tid >> 6;               // 0..7
  const int lane = tid & 63;
  const int lane15 = lane & 15;
  const int quad = lane >> 4;
  const int row0 = blockIdx.x * 128;

  // --- Stage W from fp32 (coalesced), converting to bf16 in flight ---
  const float4* w32 = (const float4*)Wf;
#pragma unroll
  for (int it = 0; it < 4; ++it) {
    int c = it * 512 + tid;  // 0..2047 uint4 chunks (8 bf16 each)
    int r = c >> 4;
    int ck = c & 15;
    float4 f0 = w32[(size_t)r * 32 + 2 * ck];
    float4 f1 = w32[(size_t)r * 32 + 2 * ck + 1];
    uint4 uu = make_uint4(pack_bf16x2(f0.x, f0.y), pack_bf16x2(f0.z, f0.w),
                          pack_bf16x2(f1.x, f1.y), pack_bf16x2(f1.z, f1.w));
    *(uint4*)&Ws[r * 136 + ck * 8] = uu;
  }

  // --- Stage H (coalesced) ---
  if (F32IN) {
    const float4* in32 = (const float4*)in_v;  // 32 chunks of 4 floats per row
#pragma unroll
    for (int it = 0; it < 8; ++it) {
      int c = it * 512 + tid;  // 0..4095
      int r = c >> 5;
      int ck = c & 31;
      float4 g = make_float4(0.f, 0.f, 0.f, 0.f);
      if (row0 + r < M) g = in32[(size_t)(row0 + r) * 32 + ck];
      uint2 pk = make_uint2(pack_bf16x2(g.x, g.y), pack_bf16x2(g.z, g.w));
      *(uint2*)&Hs[r * 136 + ck * 4] = pk;
    }
  } else {
    const uint4* in16 = (const uint4*)in_v;  // 16 chunks per bf16 row
#pragma unroll
    for (int it = 0; it < 4; ++it) {
      int c = it * 512 + tid;  // 0..2047
      int r = c >> 4;
      int ck = c & 15;
      uint4 g = make_uint4(0, 0, 0, 0);
      if (row0 + r < M) g = in16[(size_t)(row0 + r) * 16 + ck];
      *(uint4*)&Hs[r * 136 + ck * 8] = g;
    }
  }
  __syncthreads();

  // Wave w owns output rows m = row0 + w*16 + lane15.
  const int mrow = row0 + w * 16 + lane15;
  bf16v8 hf[4];
#pragma unroll
  for (int kt = 0; kt < 4; ++kt)
    hf[kt] = *(const bf16v8*)&Hs[(w * 16 + lane15) * 136 + kt * 32 + quad * 8];

  f32v4 acc[8];
#pragma unroll
  for (int nt = 0; nt < 8; ++nt) acc[nt] = (f32v4){0.f, 0.f, 0.f, 0.f};

#pragma unroll
  for (int kt = 0; kt < 4; ++kt) {
    const int ko = kt * 32 + quad * 8;
#pragma unroll
    for (int nt = 0; nt < 8; ++nt) {
      bf16v8 a = *(const bf16v8*)&Ws[(nt * 16 + lane15) * 136 + ko];
      acc[nt] = __builtin_amdgcn_mfma_f32_16x16x32_bf16(a, hf[kt], acc[nt], 0, 0, 0);
    }
  }

  // --- Epilogue: lane holds Y[mrow][nt*16 + quad*4 + r], r=0..3 ---
  if (mrow < M) {
#pragma unroll
    for (int nt = 0; nt < 8; ++nt) {
      uint2 pk;
      pk.x = pack_bf16x2(acc[nt][0], acc[nt][1]);
      pk.y = pack_bf16x2(acc[nt][2], acc[nt][3]);
      *(uint2*)&out[(size_t)mrow * D + nt * 16 + quad * 4] = pk;
    }
  }
}

// ---------------------------------------------------------------------------
// Fused SpMM (round-11/round-14 form, the measured optimum of the ILP
// family: 1 row = 61us latency-bound, 2 rows = 37us, 4 rows = 40us+).
// TWO rows per wave, processed concurrently: one scalar fetch covers both
// rowptr spans; both rows' record loads and gathers in flight together
// (8 outstanding gathers/wave).  2 edge-parity groups x 32 lanes; lane l
// owns dims 4l..4l+3; uint2 gathers (one instr = 2 rows x 256B); padded
// rows keep the loop branch-free.  Epilogue parallel: half g=0 finalizes
// rowA while g=1 does rowB.
// MODE 0: bias+sigmoid -> bf16.  MODE 1: bias+row-softmax -> fp32.
// ---------------------------------------------------------------------------
template <int MODE>
__global__ __launch_bounds__(256) void spmm_fused(
    const unsigned int* __restrict__ h, const int2* __restrict__ sorted,
    const int* __restrict__ rowptr,
    const float* __restrict__ bias, void* __restrict__ out_v, int n) {
  const int wave = threadIdx.x >> 6;
  const int lane = threadIdx.x & 63;
  const int g = lane >> 5;   // parity group / epilogue row select
  const int l = lane & 31;   // dim chunk: owns dims 4l..4l+3
  int pairid = blockIdx.x * 4 + wave;
  int rowA = __builtin_amdgcn_readfirstlane(pairid * 2);
  if (rowA >= n) return;
  const int rowB = rowA + 1;
  const bool hasB = rowB < n;
  const int sA = __builtin_amdgcn_readfirstlane(rowptr[rowA]);
  const int eA = __builtin_amdgcn_readfirstlane(rowptr[rowA + 1]);
  const int eB = hasB ? __builtin_amdgcn_readfirstlane(rowptr[rowA + 2]) : eA;
  const int lpA = eA - sA;
  const int lpB = eB - eA;

  const char* hb = (const char*)h;
  const char* sb = (const char*)sorted;
  const unsigned lb = (unsigned)l << 3;
  unsigned soA = (unsigned)sA << 3;
  unsigned soB = (unsigned)eA << 3;

  float4 bb = ((const float4*)bias)[l];  // hoisted; overlaps edge walk

  float a0 = 0.f, a1 = 0.f, a2 = 0.f, a3 = 0.f;   // rowA
  float b0 = 0.f, b1 = 0.f, b2 = 0.f, b3 = 0.f;   // rowB

  const int m = (lpA < lpB) ? lpA : lpB;
  int j = 0;
  // --- joint loop: both rows' batches in flight together ---
  for (; j < m; j += 8, soA += 64, soB += 64) {
    int4 pa0 = *(const int4*)(sb + soA);
    int4 pa1 = *(const int4*)(sb + soA + 16);
    int4 pa2 = *(const int4*)(sb + soA + 32);
    int4 pa3 = *(const int4*)(sb + soA + 48);
    int4 pb0 = *(const int4*)(sb + soB);
    int4 pb1 = *(const int4*)(sb + soB + 16);
    int4 pb2 = *(const int4*)(sb + soB + 32);
    int4 pb3 = *(const int4*)(sb + soB + 48);
    unsigned ba0 = (unsigned)(g ? pa0.z : pa0.x);
    unsigned ba1 = (unsigned)(g ? pa1.z : pa1.x);
    unsigned ba2 = (unsigned)(g ? pa2.z : pa2.x);
    unsigned ba3 = (unsigned)(g ? pa3.z : pa3.x);
    unsigned bb0 = (unsigned)(g ? pb0.z : pb0.x);
    unsigned bb1 = (unsigned)(g ? pb1.z : pb1.x);
    unsigned bb2 = (unsigned)(g ? pb2.z : pb2.x);
    unsigned bb3 = (unsigned)(g ? pb3.z : pb3.x);
    uint2 ua0 = *(const uint2*)(hb + (ba0 + lb));
    uint2 ua1 = *(const uint2*)(hb + (ba1 + lb));
    uint2 ua2 = *(const uint2*)(hb + (ba2 + lb));
    uint2 ua3 = *(const uint2*)(hb + (ba3 + lb));
    uint2 ub0 = *(const uint2*)(hb + (bb0 + lb));
    uint2 ub1 = *(const uint2*)(hb + (bb1 + lb));
    uint2 ub2 = *(const uint2*)(hb + (bb2 + lb));
    uint2 ub3 = *(const uint2*)(hb + (bb3 + lb));
    float va0 = __int_as_float(g ? pa0.w : pa0.y);
    float va1 = __int_as_float(g ? pa1.w : pa1.y);
    float va2 = __int_as_float(g ? pa2.w : pa2.y);
    float va3 = __int_as_float(g ? pa3.w : pa3.y);
    float vb0 = __int_as_float(g ? pb0.w : pb0.y);
    float vb1 = __int_as_float(g ? pb1.w : pb1.y);
    float vb2 = __int_as_float(g ? pb2.w : pb2.y);
    float vb3 = __int_as_float(g ? pb3.w : pb3.y);
    a0 = fmaf(va0, bf_lo(ua0.x), a0); a1 = fmaf(va0, bf_hi(ua0.x), a1);
    a2 = fmaf(va0, bf_lo(ua0.y), a2); a3 = fmaf(va0, bf_hi(ua0.y), a3);
    a0 = fmaf(va1, bf_lo(ua1.x), a0); a1 = fmaf(va1, bf_hi(ua1.x), a1);
    a2 = fmaf(va1, bf_lo(ua1.y), a2); a3 = fmaf(va1, bf_hi(ua1.y), a3);
    a0 = fmaf(va2, bf_lo(ua2.x), a0); a1 = fmaf(va2, bf_hi(ua2.x), a1);
    a2 = fmaf(va2, bf_lo(ua2.y), a2); a3 = fmaf(va2, bf_hi(ua2.y), a3);
    a0 = fmaf(va3, bf_lo(ua3.x), a0); a1 = fmaf(va3, bf_hi(ua3.x), a1);
    a2 = fmaf(va3, bf_lo(ua3.y), a2); a3 = fmaf(va3, bf_hi(ua3.y), a3);
    b0 = fmaf(vb0, bf_lo(ub0.x), b0); b1 = fmaf(vb0, bf_hi(ub0.x), b1);
    b2 = fmaf(vb0, bf_lo(ub0.y), b2); b3 = fmaf(vb0, bf_hi(ub0.y), b3);
    b0 = fmaf(vb1, bf_lo(ub1.x), b0); b1 = fmaf(vb1, bf_hi(ub1.x), b1);
    b2 = fmaf(vb1, bf_lo(ub1.y), b2); b3 = fmaf(vb1, bf_hi(ub1.y), b3);
    b0 = fmaf(vb2, bf_lo(ub2.x), b0); b1 = fmaf(vb2, bf_hi(ub2.x), b1);
    b2 = fmaf(vb2, bf_lo(ub2.y), b2); b3 = fmaf(vb2, bf_hi(ub2.y), b3);
    b0 = fmaf(vb3, bf_lo(ub3.x), b0); b1 = fmaf(vb3, bf_hi(ub3.x), b1);
    b2 = fmaf(vb3, bf_lo(ub3.y), b2); b3 = fmaf(vb3, bf_hi(ub3.y), b3);
  }
  // --- rowA tail (lpA > m) ---
  for (int ja = j; ja < lpA; ja += 8, soA += 64) {
    int4 p0 = *(const int4*)(sb + soA);
    int4 p1 = *(const int4*)(sb + soA + 16);
    int4 p2 = *(const int4*)(sb + soA + 32);
    int4 p3 = *(const int4*)(sb + soA + 48);
    unsigned c0 = (unsigned)(g ? p0.z : p0.x);
    unsigned c1 = (unsigned)(g ? p1.z : p1.x);
    unsigned c2 = (unsigned)(g ? p2.z : p2.x);
    unsigned c3 = (unsigned)(g ? p3.z : p3.x);
    uint2 u0 = *(const uint2*)(hb + (c0 + lb));
    uint2 u1 = *(const uint2*)(hb + (c1 + lb));
    uint2 u2 = *(const uint2*)(hb + (c2 + lb));
    uint2 u3 = *(const uint2*)(hb + (c3 + lb));
    float v0 = __int_as_float(g ? p0.w : p0.y);
    float v1 = __int_as_float(g ? p1.w : p1.y);
    float v2 = __int_as_float(g ? p2.w : p2.y);
    float v3 = __int_as_float(g ? p3.w : p3.y);
    a0 = fmaf(v0, bf_lo(u0.x), a0); a1 = fmaf(v0, bf_hi(u0.x), a1);
    a2 = fmaf(v0, bf_lo(u0.y), a2); a3 = fmaf(v0, bf_hi(u0.y), a3);
    a0 = fmaf(v1, bf_lo(u1.x), a0); a1 = fmaf(v1, bf_hi(u1.x), a1);
    a2 = fmaf(v1, bf_lo(u1.y), a2); a3 = fmaf(v1, bf_hi(u1.y), a3);
    a0 = fmaf(v2, bf_lo(u2.x), a0); a1 = fmaf(v2, bf_hi(u2.x), a1);
    a2 = fmaf(v2, bf_lo(u2.y), a2); a3 = fmaf(v2, bf_hi(u2.y), a3);
    a0 = fmaf(v3, bf_lo(u3.x), a0); a1 = fmaf(v3, bf_hi(u3.x), a1);
    a2 = fmaf(v3, bf_lo(u3.y), a2); a3 = fmaf(v3, bf_hi(u3.y), a3);
  }
  // --- rowB tail (lpB > m) ---
  for (int jb = j; jb < lpB; jb += 8, soB += 64) {
    int4 p0 = *(const int4*)(sb + soB);
    int4 p1 = *(const int4*)(sb + soB + 16);
    int4 p2 = *(const int4*)(sb + soB + 32);
    int4 p3 = *(const int4*)(sb + soB + 48);
    unsigned c0 = (unsigned)(g ? p0.z : p0.x);
    unsigned c1 = (unsigned)(g ? p1.z : p1.x);
    unsigned c2 = (unsigned)(g ? p2.z : p2.x);
    unsigned c3 = (unsigned)(g ? p3.z : p3.x);
    uint2 u0 = *(const uint2*)(hb + (c0 + lb));
    uint2 u1 = *(const uint2*)(hb + (c1 + lb));
    uint2 u2 = *(const uint2*)(hb + (c2 + lb));
    uint2 u3 = *(const uint2*)(hb + (c3 + lb));
    float v0 = __int_as_float(g ? p0.w : p0.y);
    float v1 = __int_as_float(g ? p1.w : p1.y);
    float v2 = __int_as_float(g ? p2.w : p2.y);
    float v3 = __int_as_float(g ? p3.w : p3.y);
    b0 = fmaf(v0, bf_lo(u0.x), b0); b1 = fmaf(v0, bf_hi(u0.x), b1);
    b2 = fmaf(v0, bf_lo(u0.y), b2); b3 = fmaf(v0, bf_hi(u0.y), b3);
    b0 = fmaf(v1, bf_lo(u1.x), b0); b1 = fmaf(v1, bf_hi(u1.x), b1);
    b2 = fmaf(v1, bf_lo(u1.y), b2); b3 = fmaf(v1, bf_hi(u1.y), b3);
    b0 = fmaf(v2, bf_lo(u2.x), b0); b1 = fmaf(v2, bf_hi(u2.x), b1);
    b2 = fmaf(v2, bf_lo(u2.y), b2); b3 = fmaf(v2, bf_hi(u2.y), b3);
    b0 = fmaf(v3, bf_lo(u3.x), b0); b1 = fmaf(v3, bf_hi(u3.x), b1);
    b2 = fmaf(v3, bf_lo(u3.y), b2); b3 = fmaf(v3, bf_hi(u3.y), b3);
  }

  // Cross-parity merge: afterwards BOTH halves hold each row's full sums.
  a0 += __shfl_xor(a0, 32); a1 += __shfl_xor(a1, 32);
  a2 += __shfl_xor(a2, 32); a3 += __shfl_xor(a3, 32);
  b0 += __shfl_xor(b0, 32); b1 += __shfl_xor(b1, 32);
  b2 += __shfl_xor(b2, 32); b3 += __shfl_xor(b3, 32);

  // Half g finalizes row (g ? rowB : rowA).
  float r0 = (g ? b0 : a0) + bb.x;
  float r1 = (g ? b1 : a1) + bb.y;
  float r2 = (g ? b2 : a2) + bb.z;
  float r3 = (g ? b3 : a3) + bb.w;
  const int row = g ? rowB : rowA;
  const bool doStore = (g == 0) || hasB;

  if (MODE == 0) {
    if (doStore) {
      uint2 pk;
      pk.x = pack_bf16x2(1.0f / (1.0f + __expf(-r0)), 1.0f / (1.0f + __expf(-r1)));
      pk.y = pack_bf16x2(1.0f / (1.0f + __expf(-r2)), 1.0f / (1.0f + __expf(-r3)));
      ((uint2*)out_v)[(size_t)row * 32 + l] = pk;
    }
  } else {
    // Per-half softmax over the 32 lanes of this half (offsets < 32 stay
    // within the half).
    float mx = fmaxf(fmaxf(r0, r1), fmaxf(r2, r3));
#pragma unroll
    for (int off = 16; off; off >>= 1) mx = fmaxf(mx, __shfl_xor(mx, off));
    float e0 = __expf(r0 - mx), e1 = __expf(r1 - mx);
    float e2 = __expf(r2 - mx), e3 = __expf(r3 - mx);
    float s = (e0 + e1) + (e2 + e3);
#pragma unroll
    for (int off = 16; off; off >>= 1) s += __shfl_xor(s, off);
    float inv = 1.0f / s;
    if (doStore) {
      ((float4*)out_v)[(size_t)row * 32 + l] =
          make_float4(e0 * inv, e1 * inv, e2 * inv, e3 * inv);
    }
  }
}

// ---------------------------------------------------------------------------
extern "C" void kernel_launch(void* const* d_in, const int* in_sizes, int n_in,
                              void* d_out, int out_size, void* d_ws, size_t ws_size,
                              hipStream_t stream) {
  const float* x  = (const float*)d_in[0];
  const float* ev = (const float*)d_in[1];
  const float* W1 = (const float*)d_in[2];
  const float* b1 = (const float*)d_in[3];
  const float* W2 = (const float*)d_in[4];
  const float* b2 = (const float*)d_in[5];
  const float* W3 = (const float*)d_in[6];
  const float* b3 = (const float*)d_in[7];
  const int* es = (const int*)d_in[8];
  const int* ed = (const int*)d_in[9];

  const int N = in_sizes[0] / D;
  const int E = in_sizes[1];

  // Workspace layout (all 16B-aligned).  sorted holds up to E + 7N records
  // (worst-case pad8 expansion); rowptr has N+1 entries (+pad).
  char* p = (char*)d_ws;
  unsigned int* BA = (unsigned int*)p; p += (size_t)N * 64 * sizeof(unsigned int);
  unsigned int* BB = (unsigned int*)p; p += (size_t)N * 64 * sizeof(unsigned int);
  int2* sorted = (int2*)p;          p += ((size_t)E + 7 * (size_t)N + 8) * sizeof(int2);
  int2* coarse = (int2*)p;          p += ((size_t)E + 8) * sizeof(int2);
  int* Hc = (int*)p;                p += (size_t)PBLK * NBK * sizeof(int);
  int* Bbase = (int*)p;             p += (NBK + 8) * sizeof(int);
  int* count  = (int*)p;            p += (size_t)N * sizeof(int);
  int* rowptr = (int*)p;            p += ((size_t)N + 8) * sizeof(int);
  int* blockSums = (int*)p;         p += 1024 * sizeof(int);

  const int nblk256 = (N + 255) / 256;
  const int nblkScan = (N + SCAN_CHUNK - 1) / SCAN_CHUNK;
  const int pairgrid = ((N + 1) / 2 + 3) / 4;  // 2 rows/wave, 4 waves/block
  const int dense_grid = (N + 127) / 128;
  const int nbuckets = (N + 127) >> 7;         // <= NBK for N <= 131072
  const int chunk = (E + PBLK - 1) / PBLK;

  // --- Build padded dst-sorted CSR (zero device-scope atomics) ---
  coarse_hist<<<PBLK, 256, 0, stream>>>(ed, Hc, E, chunk);
  coarse_scan_tot<<<1, 1024, 0, stream>>>(Hc, Bbase, PBLK);
  coarse_bases<<<NBK / 256, 256, 0, stream>>>(Hc, Bbase, PBLK);
  coarse_scatter<<<PBLK, 256, 0, stream>>>(es, ed, ev, Hc, coarse, E, chunk);
  fine_hist<<<nbuckets, 256, 0, stream>>>(coarse, Bbase, count, N);
  scan_blocks<<<nblkScan, 256, 0, stream>>>(count, rowptr, blockSums, N);
  scan_top<<<1, 256, 0, stream>>>(blockSums, nblkScan);
  add_offsets<<<nblk256, 256, 0, stream>>>(rowptr, blockSums, count, sorted, N);
  fine_scatter<<<nbuckets, 256, 0, stream>>>(coarse, Bbase, rowptr, sorted, N);

  // --- Layer 1: Y1 = x@W1^T (fp32 in), h1 = sigmoid(A@Y1 + b1) ---
  dense_nt<1><<<dense_grid, 512, 0, stream>>>(x, W1, (unsigned short*)BA, N);
  spmm_fused<0><<<pairgrid, 256, 0, stream>>>(BA, sorted, rowptr, b1, BB, N);
  // --- Layer 2 ---
  dense_nt<0><<<dense_grid, 512, 0, stream>>>(BB, W2, (unsigned short*)BA, N);
  spmm_fused<0><<<pairgrid, 256, 0, stream>>>(BA, sorted, rowptr, b2, BB, N);
  // --- Layer 3: Y3 = h2@W3^T, out = softmax(A@Y3 + b3) ---
  dense_nt<0><<<dense_grid, 512, 0, stream>>>(BB, W3, (unsigned short*)BA, N);
  spmm_fused<1><<<pairgrid, 256, 0, stream>>>(BA, sorted, rowptr, b3, d_out, N);
}

// Round 14
// 320.842 us; speedup vs baseline: 1.0661x; 1.0661x over previous
//
#include <hip/hip_runtime.h>
#include <hip/hip_bf16.h>
#include <cstdint>
#include <cstddef>

#define D 128
#define SCAN_CHUNK 1024
#define NBK 1024    // coarse buckets (dst >> 7); supports n <= 131072
#define PBLK 128    // blocks for coarse hist/scatter
#define FS_CAP 4096 // LDS staging capacity (records) for fine_scatter

typedef __attribute__((ext_vector_type(8))) __bf16 bf16v8;
typedef __attribute__((ext_vector_type(4))) float f32v4;

// Round-to-nearest-even fp32 -> bf16 (bits), packed pair.
__device__ inline unsigned int pack_bf16x2(float a, float b) {
  unsigned int ua = __float_as_uint(a);
  unsigned int ub = __float_as_uint(b);
  ua = (ua + 0x7fffu + ((ua >> 16) & 1u)) >> 16;
  ub = (ub + 0x7fffu + ((ub >> 16) & 1u)) >> 16;
  return ua | (ub << 16);
}
__device__ inline float bf_lo(unsigned int u) { return __uint_as_float(u << 16); }
__device__ inline float bf_hi(unsigned int u) { return __uint_as_float(u & 0xffff0000u); }

// ---------------------------------------------------------------------------
// Two-level counting sort, round 14: zero device-scope atomics AND fixed
// round-13 defects: (a) bucket-base computation is parallel (col_prefix 4
// blocks + bucket_scan), (b) fine scatter stages each bucket's contiguous
// padded segment in LDS and flushes coalesced int4 (kills the 41MB random-
// 8B-store write amplification; padding comes free from the zeroed stage).
// Final `sorted` format unchanged: records (src<<8, val), rows padded to
// multiple of 8 with (0,0); rowptr[N+1] deltas are padded lengths.
// ---------------------------------------------------------------------------

// Coarse histogram: LDS 1024-bucket hist per block, coalesced flush.
__global__ __launch_bounds__(256) void coarse_hist(
    const int* __restrict__ dst, int* __restrict__ Hc, int E, int chunk) {
  __shared__ int h[NBK];
  for (int i = threadIdx.x; i < NBK; i += 256) h[i] = 0;
  __syncthreads();
  int s = blockIdx.x * chunk;
  int e = s + chunk; if (e > E) e = E;
  for (int i = s + threadIdx.x; i < e; i += 256)
    atomicAdd(&h[dst[i] >> 7], 1);
  __syncthreads();
  for (int i = threadIdx.x; i < NBK; i += 256)
    Hc[(size_t)blockIdx.x * NBK + i] = h[i];
}

// Per-bucket column prefix over blocks (in place) + bucket totals.
// Reads/writes coalesced across threads for each bl.  grid = NBK/256.
__global__ __launch_bounds__(256) void col_prefix(
    int* __restrict__ Hc, int* __restrict__ Btot, int nblk) {
  int b = blockIdx.x * 256 + threadIdx.x;
  int run = 0;
  for (int bl = 0; bl < nblk; ++bl) {
    int c = Hc[(size_t)bl * NBK + b];
    Hc[(size_t)bl * NBK + b] = run;
    run += c;
  }
  Btot[b] = run;
}

// Exclusive scan of bucket totals -> Bbase[NBK+1].
__global__ __launch_bounds__(1024) void bucket_scan(
    const int* __restrict__ Btot, int* __restrict__ Bbase) {
  __shared__ int sdata[NBK];
  const int t = threadIdx.x;
  int s = Btot[t];
  sdata[t] = s;
  __syncthreads();
  for (int off = 1; off < NBK; off <<= 1) {
    int x = (t >= off) ? sdata[t - off] : 0;
    __syncthreads();
    sdata[t] += x;
    __syncthreads();
  }
  Bbase[t] = sdata[t] - s;  // exclusive
  if (t == NBK - 1) Bbase[NBK] = sdata[t];
}

// Coarse scatter: LDS cursors seeded Bbase[b] + per-block prefix; record
// packs dst low 7 bits into the free low byte of src<<8.
__global__ __launch_bounds__(256) void coarse_scatter(
    const int* __restrict__ src, const int* __restrict__ dst,
    const float* __restrict__ val, const int* __restrict__ Hc,
    const int* __restrict__ Bbase, int2* __restrict__ coarse,
    int E, int chunk) {
  __shared__ int cur[NBK];
  for (int i = threadIdx.x; i < NBK; i += 256)
    cur[i] = Bbase[i] + Hc[(size_t)blockIdx.x * NBK + i];
  __syncthreads();
  int s = blockIdx.x * chunk;
  int e = s + chunk; if (e > E) e = E;
  for (int i = s + threadIdx.x; i < e; i += 256) {
    int d = dst[i];
    int pos = atomicAdd(&cur[d >> 7], 1);   // LDS atomic
    coarse[pos] = make_int2((src[i] << 8) | (d & 127), __float_as_int(val[i]));
  }
}

// Fine histogram per 128-row bucket -> count[] (coalesced; no memset).
__global__ __launch_bounds__(256) void fine_hist(
    const int2* __restrict__ coarse, const int* __restrict__ Bbase,
    int* __restrict__ count, int n) {
  __shared__ int cnt[128];
  if (threadIdx.x < 128) cnt[threadIdx.x] = 0;
  __syncthreads();
  const int b = blockIdx.x;
  const int s = Bbase[b], e = Bbase[b + 1];
  for (int i = s + threadIdx.x; i < e; i += 256)
    atomicAdd(&cnt[coarse[i].x & 127], 1);  // LDS atomic
  __syncthreads();
  int r = b * 128 + threadIdx.x;
  if (threadIdx.x < 128 && r < n) count[r] = cnt[threadIdx.x];
}

// Scans PADDED lengths: pad8(c) = (c+7)&~7.
__global__ __launch_bounds__(256) void scan_blocks(
    const int* __restrict__ count, int* __restrict__ rowptr,
    int* __restrict__ blockSums, int n) {
  __shared__ int sdata[256];
  const int tid = threadIdx.x;
  const int base = blockIdx.x * SCAN_CHUNK;
  int v[4];
#pragma unroll
  for (int k = 0; k < 4; ++k) {
    int idx = base + tid * 4 + k;
    int c = (idx < n) ? count[idx] : 0;
    v[k] = (c + 7) & ~7;
  }
  int s = v[0] + v[1] + v[2] + v[3];
  sdata[tid] = s;
  __syncthreads();
  for (int off = 1; off < 256; off <<= 1) {
    int x = (tid >= off) ? sdata[tid - off] : 0;
    __syncthreads();
    sdata[tid] += x;
    __syncthreads();
  }
  int run = sdata[tid] - s;
#pragma unroll
  for (int k = 0; k < 4; ++k) {
    int idx = base + tid * 4 + k;
    if (idx < n) rowptr[idx] = run;
    run += v[k];
  }
  if (tid == 255) blockSums[blockIdx.x] = sdata[255];
}

__global__ __launch_bounds__(256) void scan_top(int* __restrict__ bs, int nblk) {
  __shared__ int sdata[256];
  const int tid = threadIdx.x;
  int v[4];
#pragma unroll
  for (int k = 0; k < 4; ++k) {
    int idx = tid * 4 + k;
    v[k] = (idx < nblk) ? bs[idx] : 0;
  }
  int s = v[0] + v[1] + v[2] + v[3];
  sdata[tid] = s;
  __syncthreads();
  for (int off = 1; off < 256; off <<= 1) {
    int x = (tid >= off) ? sdata[tid - off] : 0;
    __syncthreads();
    sdata[tid] += x;
    __syncthreads();
  }
  int run = sdata[tid] - s;
#pragma unroll
  for (int k = 0; k < 4; ++k) {
    int idx = tid * 4 + k;
    if (idx < nblk) { int t = v[k]; bs[idx] = run; run += t; }
  }
}

// Finalize rowptr (+ terminator).  Padding slots are written by the staged
// fine_scatter, not here.
__global__ __launch_bounds__(256) void add_offsets(
    int* __restrict__ rowptr, const int* __restrict__ bs,
    const int* __restrict__ count, int n) {
  int i = blockIdx.x * 256 + threadIdx.x;
  if (i < n) {
    int v = rowptr[i] + bs[i >> 10];
    rowptr[i] = v;
    if (i == n - 1) rowptr[n] = v + ((count[i] + 7) & ~7);
  }
}

// Fine scatter, LDS-staged: a bucket's 128 rows form ONE contiguous padded
// segment [rowptr[128b], rowptr[128b+128]) whose length is a multiple of 8.
// Stage it zeroed in LDS (padding free), place records via LDS cursors, then
// flush coalesced as int4 — no random-8B-store write amplification.
// Fallback (segment > FS_CAP, statistically impossible but data-independent
// correctness requires it): direct scatter + explicit padding fill.
__global__ __launch_bounds__(256) void fine_scatter(
    const int2* __restrict__ coarse, const int* __restrict__ Bbase,
    const int* __restrict__ rowptr, int2* __restrict__ sorted, int n) {
  __shared__ int rowbase[129];
  __shared__ int lcur[128];
  __shared__ __align__(16) int2 stage[FS_CAP];
  const int b = blockIdx.x;
  const int r0 = b * 128;
  for (int i = threadIdx.x; i < 129; i += 256) {
    int r = r0 + i;
    rowbase[i] = rowptr[(r < n) ? r : n];
  }
  __syncthreads();
  const int segS = rowbase[0];
  const int segLen = rowbase[128] - segS;
  const int s = Bbase[b], e = Bbase[b + 1];

  if (segLen <= FS_CAP) {
    int4* st4 = (int4*)stage;
    for (int i = threadIdx.x; i < (segLen >> 1); i += 256)
      st4[i] = make_int4(0, 0, 0, 0);
    if (threadIdx.x < 128) lcur[threadIdx.x] = rowbase[threadIdx.x] - segS;
    __syncthreads();
    for (int i = s + threadIdx.x; i < e; i += 256) {
      int2 rec = coarse[i];
      int pos = atomicAdd(&lcur[rec.x & 127], 1);  // LDS atomic
      stage[pos] = make_int2(rec.x & (int)0xFFFFFF00, rec.y);
    }
    __syncthreads();
    int4* out4 = (int4*)(sorted + segS);  // segS multiple of 8 -> 16B aligned
    for (int i = threadIdx.x; i < (segLen >> 1); i += 256)
      out4[i] = st4[i];
  } else {
    if (threadIdx.x < 128) lcur[threadIdx.x] = rowbase[threadIdx.x];
    __syncthreads();
    for (int i = s + threadIdx.x; i < e; i += 256) {
      int2 rec = coarse[i];
      int pos = atomicAdd(&lcur[rec.x & 127], 1);
      sorted[pos] = make_int2(rec.x & (int)0xFFFFFF00, rec.y);
    }
    __syncthreads();
    for (int r = threadIdx.x; r < 128 && r0 + r < n; r += 256) {
      int end = rowbase[r + 1];
      for (int k = lcur[r]; k < end; ++k) sorted[k] = make_int2(0, 0);
    }
  }
}

// ---------------------------------------------------------------------------
// Dense transform Y = in @ W^T (round-14 structure + inline W cast).
// Operand-swapped MFMA (A=W frag, B=H frag -> lane holds Y[row][4 consecutive
// cols] -> 8 x 8B uint2 stores per lane), coalesced LDS staging for H and W,
// 512-thread blocks (16 waves/CU at the 2-block LDS limit).  W is staged
// DIRECTLY from the fp32 input with in-flight bf16 conversion.
// ---------------------------------------------------------------------------
template <int F32IN>
__global__ __launch_bounds__(512) void dense_nt(
    const void* __restrict__ in_v, const float* __restrict__ Wf,
    unsigned short* __restrict__ out, int M) {
  __shared__ __align__(16) unsigned short Hs[128 * 136];
  __shared__ __align__(16) unsigned short Ws[128 * 136];

  const int tid = threadIdx.x;          // 0..511
  const int w = tid >> 6;               // 0..7
  const int lane = tid & 63;
  const int lane15 = lane & 15;
  const int quad = lane >> 4;
  const int row0 = blockIdx.x * 128;

  // --- Stage W from fp32 (coalesced), converting to bf16 in flight ---
  const float4* w32 = (const float4*)Wf;
#pragma unroll
  for (int it = 0; it < 4; ++it) {
    int c = it * 512 + tid;  // 0..2047 uint4 chunks (8 bf16 each)
    int r = c >> 4;
    int ck = c & 15;
    float4 f0 = w32[(size_t)r * 32 + 2 * ck];
    float4 f1 = w32[(size_t)r * 32 + 2 * ck + 1];
    uint4 uu = make_uint4(pack_bf16x2(f0.x, f0.y), pack_bf16x2(f0.z, f0.w),
                          pack_bf16x2(f1.x, f1.y), pack_bf16x2(f1.z, f1.w));
    *(uint4*)&Ws[r * 136 + ck * 8] = uu;
  }

  // --- Stage H (coalesced) ---
  if (F32IN) {
    const float4* in32 = (const float4*)in_v;  // 32 chunks of 4 floats per row
#pragma unroll
    for (int it = 0; it < 8; ++it) {
      int c = it * 512 + tid;  // 0..4095
      int r = c >> 5;
      int ck = c & 31;
      float4 g = make_float4(0.f, 0.f, 0.f, 0.f);
      if (row0 + r < M) g = in32[(size_t)(row0 + r) * 32 + ck];
      uint2 pk = make_uint2(pack_bf16x2(g.x, g.y), pack_bf16x2(g.z, g.w));
      *(uint2*)&Hs[r * 136 + ck * 4] = pk;
    }
  } else {
    const uint4* in16 = (const uint4*)in_v;  // 16 chunks per bf16 row
#pragma unroll
    for (int it = 0; it < 4; ++it) {
      int c = it * 512 + tid;  // 0..2047
      int r = c >> 4;
      int ck = c & 15;
      uint4 g = make_uint4(0, 0, 0, 0);
      if (row0 + r < M) g = in16[(size_t)(row0 + r) * 16 + ck];
      *(uint4*)&Hs[r * 136 + ck * 8] = g;
    }
  }
  __syncthreads();

  // Wave w owns output rows m = row0 + w*16 + lane15.
  const int mrow = row0 + w * 16 + lane15;
  bf16v8 hf[4];
#pragma unroll
  for (int kt = 0; kt < 4; ++kt)
    hf[kt] = *(const bf16v8*)&Hs[(w * 16 + lane15) * 136 + kt * 32 + quad * 8];

  f32v4 acc[8];
#pragma unroll
  for (int nt = 0; nt < 8; ++nt) acc[nt] = (f32v4){0.f, 0.f, 0.f, 0.f};

#pragma unroll
  for (int kt = 0; kt < 4; ++kt) {
    const int ko = kt * 32 + quad * 8;
#pragma unroll
    for (int nt = 0; nt < 8; ++nt) {
      bf16v8 a = *(const bf16v8*)&Ws[(nt * 16 + lane15) * 136 + ko];
      acc[nt] = __builtin_amdgcn_mfma_f32_16x16x32_bf16(a, hf[kt], acc[nt], 0, 0, 0);
    }
  }

  // --- Epilogue: lane holds Y[mrow][nt*16 + quad*4 + r], r=0..3 ---
  if (mrow < M) {
#pragma unroll
    for (int nt = 0; nt < 8; ++nt) {
      uint2 pk;
      pk.x = pack_bf16x2(acc[nt][0], acc[nt][1]);
      pk.y = pack_bf16x2(acc[nt][2], acc[nt][3]);
      *(uint2*)&out[(size_t)mrow * D + nt * 16 + quad * 4] = pk;
    }
  }
}

// ---------------------------------------------------------------------------
// Fused SpMM (round-11 form, the measured optimum of the ILP family:
// 1 row = 61us latency-bound, 2 rows = 37us, 4 rows = 40us+).
// TWO rows per wave, processed concurrently.  2 edge-parity groups x 32
// lanes; lane l owns dims 4l..4l+3; uint2 gathers; padded rows keep the
// loop branch-free; epilogue parallel across halves.
// MODE 0: bias+sigmoid -> bf16.  MODE 1: bias+row-softmax -> fp32.
// ---------------------------------------------------------------------------
template <int MODE>
__global__ __launch_bounds__(256) void spmm_fused(
    const unsigned int* __restrict__ h, const int2* __restrict__ sorted,
    const int* __restrict__ rowptr,
    const float* __restrict__ bias, void* __restrict__ out_v, int n) {
  const int wave = threadIdx.x >> 6;
  const int lane = threadIdx.x & 63;
  const int g = lane >> 5;   // parity group / epilogue row select
  const int l = lane & 31;   // dim chunk: owns dims 4l..4l+3
  int pairid = blockIdx.x * 4 + wave;
  int rowA = __builtin_amdgcn_readfirstlane(pairid * 2);
  if (rowA >= n) return;
  const int rowB = rowA + 1;
  const bool hasB = rowB < n;
  const int sA = __builtin_amdgcn_readfirstlane(rowptr[rowA]);
  const int eA = __builtin_amdgcn_readfirstlane(rowptr[rowA + 1]);
  const int eB = hasB ? __builtin_amdgcn_readfirstlane(rowptr[rowA + 2]) : eA;
  const int lpA = eA - sA;
  const int lpB = eB - eA;

  const char* hb = (const char*)h;
  const char* sb = (const char*)sorted;
  const unsigned lb = (unsigned)l << 3;
  unsigned soA = (unsigned)sA << 3;
  unsigned soB = (unsigned)eA << 3;

  float4 bb = ((const float4*)bias)[l];  // hoisted; overlaps edge walk

  float a0 = 0.f, a1 = 0.f, a2 = 0.f, a3 = 0.f;   // rowA
  float b0 = 0.f, b1 = 0.f, b2 = 0.f, b3 = 0.f;   // rowB

  const int m = (lpA < lpB) ? lpA : lpB;
  int j = 0;
  // --- joint loop: both rows' batches in flight together ---
  for (; j < m; j += 8, soA += 64, soB += 64) {
    int4 pa0 = *(const int4*)(sb + soA);
    int4 pa1 = *(const int4*)(sb + soA + 16);
    int4 pa2 = *(const int4*)(sb + soA + 32);
    int4 pa3 = *(const int4*)(sb + soA + 48);
    int4 pb0 = *(const int4*)(sb + soB);
    int4 pb1 = *(const int4*)(sb + soB + 16);
    int4 pb2 = *(const int4*)(sb + soB + 32);
    int4 pb3 = *(const int4*)(sb + soB + 48);
    unsigned ba0 = (unsigned)(g ? pa0.z : pa0.x);
    unsigned ba1 = (unsigned)(g ? pa1.z : pa1.x);
    unsigned ba2 = (unsigned)(g ? pa2.z : pa2.x);
    unsigned ba3 = (unsigned)(g ? pa3.z : pa3.x);
    unsigned bb0 = (unsigned)(g ? pb0.z : pb0.x);
    unsigned bb1 = (unsigned)(g ? pb1.z : pb1.x);
    unsigned bb2 = (unsigned)(g ? pb2.z : pb2.x);
    unsigned bb3 = (unsigned)(g ? pb3.z : pb3.x);
    uint2 ua0 = *(const uint2*)(hb + (ba0 + lb));
    uint2 ua1 = *(const uint2*)(hb + (ba1 + lb));
    uint2 ua2 = *(const uint2*)(hb + (ba2 + lb));
    uint2 ua3 = *(const uint2*)(hb + (ba3 + lb));
    uint2 ub0 = *(const uint2*)(hb + (bb0 + lb));
    uint2 ub1 = *(const uint2*)(hb + (bb1 + lb));
    uint2 ub2 = *(const uint2*)(hb + (bb2 + lb));
    uint2 ub3 = *(const uint2*)(hb + (bb3 + lb));
    float va0 = __int_as_float(g ? pa0.w : pa0.y);
    float va1 = __int_as_float(g ? pa1.w : pa1.y);
    float va2 = __int_as_float(g ? pa2.w : pa2.y);
    float va3 = __int_as_float(g ? pa3.w : pa3.y);
    float vb0 = __int_as_float(g ? pb0.w : pb0.y);
    float vb1 = __int_as_float(g ? pb1.w : pb1.y);
    float vb2 = __int_as_float(g ? pb2.w : pb2.y);
    float vb3 = __int_as_float(g ? pb3.w : pb3.y);
    a0 = fmaf(va0, bf_lo(ua0.x), a0); a1 = fmaf(va0, bf_hi(ua0.x), a1);
    a2 = fmaf(va0, bf_lo(ua0.y), a2); a3 = fmaf(va0, bf_hi(ua0.y), a3);
    a0 = fmaf(va1, bf_lo(ua1.x), a0); a1 = fmaf(va1, bf_hi(ua1.x), a1);
    a2 = fmaf(va1, bf_lo(ua1.y), a2); a3 = fmaf(va1, bf_hi(ua1.y), a3);
    a0 = fmaf(va2, bf_lo(ua2.x), a0); a1 = fmaf(va2, bf_hi(ua2.x), a1);
    a2 = fmaf(va2, bf_lo(ua2.y), a2); a3 = fmaf(va2, bf_hi(ua2.y), a3);
    a0 = fmaf(va3, bf_lo(ua3.x), a0); a1 = fmaf(va3, bf_hi(ua3.x), a1);
    a2 = fmaf(va3, bf_lo(ua3.y), a2); a3 = fmaf(va3, bf_hi(ua3.y), a3);
    b0 = fmaf(vb0, bf_lo(ub0.x), b0); b1 = fmaf(vb0, bf_hi(ub0.x), b1);
    b2 = fmaf(vb0, bf_lo(ub0.y), b2); b3 = fmaf(vb0, bf_hi(ub0.y), b3);
    b0 = fmaf(vb1, bf_lo(ub1.x), b0); b1 = fmaf(vb1, bf_hi(ub1.x), b1);
    b2 = fmaf(vb1, bf_lo(ub1.y), b2); b3 = fmaf(vb1, bf_hi(ub1.y), b3);
    b0 = fmaf(vb2, bf_lo(ub2.x), b0); b1 = fmaf(vb2, bf_hi(ub2.x), b1);
    b2 = fmaf(vb2, bf_lo(ub2.y), b2); b3 = fmaf(vb2, bf_hi(ub2.y), b3);
    b0 = fmaf(vb3, bf_lo(ub3.x), b0); b1 = fmaf(vb3, bf_hi(ub3.x), b1);
    b2 = fmaf(vb3, bf_lo(ub3.y), b2); b3 = fmaf(vb3, bf_hi(ub3.y), b3);
  }
  // --- rowA tail (lpA > m) ---
  for (int ja = j; ja < lpA; ja += 8, soA += 64) {
    int4 p0 = *(const int4*)(sb + soA);
    int4 p1 = *(const int4*)(sb + soA + 16);
    int4 p2 = *(const int4*)(sb + soA + 32);
    int4 p3 = *(const int4*)(sb + soA + 48);
    unsigned c0 = (unsigned)(g ? p0.z : p0.x);
    unsigned c1 = (unsigned)(g ? p1.z : p1.x);
    unsigned c2 = (unsigned)(g ? p2.z : p2.x);
    unsigned c3 = (unsigned)(g ? p3.z : p3.x);
    uint2 u0 = *(const uint2*)(hb + (c0 + lb));
    uint2 u1 = *(const uint2*)(hb + (c1 + lb));
    uint2 u2 = *(const uint2*)(hb + (c2 + lb));
    uint2 u3 = *(const uint2*)(hb + (c3 + lb));
    float v0 = __int_as_float(g ? p0.w : p0.y);
    float v1 = __int_as_float(g ? p1.w : p1.y);
    float v2 = __int_as_float(g ? p2.w : p2.y);
    float v3 = __int_as_float(g ? p3.w : p3.y);
    a0 = fmaf(v0, bf_lo(u0.x), a0); a1 = fmaf(v0, bf_hi(u0.x), a1);
    a2 = fmaf(v0, bf_lo(u0.y), a2); a3 = fmaf(v0, bf_hi(u0.y), a3);
    a0 = fmaf(v1, bf_lo(u1.x), a0); a1 = fmaf(v1, bf_hi(u1.x), a1);
    a2 = fmaf(v1, bf_lo(u1.y), a2); a3 = fmaf(v1, bf_hi(u1.y), a3);
    a0 = fmaf(v2, bf_lo(u2.x), a0); a1 = fmaf(v2, bf_hi(u2.x), a1);
    a2 = fmaf(v2, bf_lo(u2.y), a2); a3 = fmaf(v2, bf_hi(u2.y), a3);
    a0 = fmaf(v3, bf_lo(u3.x), a0); a1 = fmaf(v3, bf_hi(u3.x), a1);
    a2 = fmaf(v3, bf_lo(u3.y), a2); a3 = fmaf(v3, bf_hi(u3.y), a3);
  }
  // --- rowB tail (lpB > m) ---
  for (int jb = j; jb < lpB; jb += 8, soB += 64) {
    int4 p0 = *(const int4*)(sb + soB);
    int4 p1 = *(const int4*)(sb + soB + 16);
    int4 p2 = *(const int4*)(sb + soB + 32);
    int4 p3 = *(const int4*)(sb + soB + 48);
    unsigned c0 = (unsigned)(g ? p0.z : p0.x);
    unsigned c1 = (unsigned)(g ? p1.z : p1.x);
    unsigned c2 = (unsigned)(g ? p2.z : p2.x);
    unsigned c3 = (unsigned)(g ? p3.z : p3.x);
    uint2 u0 = *(const uint2*)(hb + (c0 + lb));
    uint2 u1 = *(const uint2*)(hb + (c1 + lb));
    uint2 u2 = *(const uint2*)(hb + (c2 + lb));
    uint2 u3 = *(const uint2*)(hb + (c3 + lb));
    float v0 = __int_as_float(g ? p0.w : p0.y);
    float v1 = __int_as_float(g ? p1.w : p1.y);
    float v2 = __int_as_float(g ? p2.w : p2.y);
    float v3 = __int_as_float(g ? p3.w : p3.y);
    b0 = fmaf(v0, bf_lo(u0.x), b0); b1 = fmaf(v0, bf_hi(u0.x), b1);
    b2 = fmaf(v0, bf_lo(u0.y), b2); b3 = fmaf(v0, bf_hi(u0.y), b3);
    b0 = fmaf(v1, bf_lo(u1.x), b0); b1 = fmaf(v1, bf_hi(u1.x), b1);
    b2 = fmaf(v1, bf_lo(u1.y), b2); b3 = fmaf(v1, bf_hi(u1.y), b3);
    b0 = fmaf(v2, bf_lo(u2.x), b0); b1 = fmaf(v2, bf_hi(u2.x), b1);
    b2 = fmaf(v2, bf_lo(u2.y), b2); b3 = fmaf(v2, bf_hi(u2.y), b3);
    b0 = fmaf(v3, bf_lo(u3.x), b0); b1 = fmaf(v3, bf_hi(u3.x), b1);
    b2 = fmaf(v3, bf_lo(u3.y), b2); b3 = fmaf(v3, bf_hi(u3.y), b3);
  }

  // Cross-parity merge: afterwards BOTH halves hold each row's full sums.
  a0 += __shfl_xor(a0, 32); a1 += __shfl_xor(a1, 32);
  a2 += __shfl_xor(a2, 32); a3 += __shfl_xor(a3, 32);
  b0 += __shfl_xor(b0, 32); b1 += __shfl_xor(b1, 32);
  b2 += __shfl_xor(b2, 32); b3 += __shfl_xor(b3, 32);

  // Half g finalizes row (g ? rowB : rowA).
  float r0 = (g ? b0 : a0) + bb.x;
  float r1 = (g ? b1 : a1) + bb.y;
  float r2 = (g ? b2 : a2) + bb.z;
  float r3 = (g ? b3 : a3) + bb.w;
  const int row = g ? rowB : rowA;
  const bool doStore = (g == 0) || hasB;

  if (MODE == 0) {
    if (doStore) {
      uint2 pk;
      pk.x = pack_bf16x2(1.0f / (1.0f + __expf(-r0)), 1.0f / (1.0f + __expf(-r1)));
      pk.y = pack_bf16x2(1.0f / (1.0f + __expf(-r2)), 1.0f / (1.0f + __expf(-r3)));
      ((uint2*)out_v)[(size_t)row * 32 + l] = pk;
    }
  } else {
    // Per-half softmax over the 32 lanes of this half (offsets < 32 stay
    // within the half).
    float mx = fmaxf(fmaxf(r0, r1), fmaxf(r2, r3));
#pragma unroll
    for (int off = 16; off; off >>= 1) mx = fmaxf(mx, __shfl_xor(mx, off));
    float e0 = __expf(r0 - mx), e1 = __expf(r1 - mx);
    float e2 = __expf(r2 - mx), e3 = __expf(r3 - mx);
    float s = (e0 + e1) + (e2 + e3);
#pragma unroll
    for (int off = 16; off; off >>= 1) s += __shfl_xor(s, off);
    float inv = 1.0f / s;
    if (doStore) {
      ((float4*)out_v)[(size_t)row * 32 + l] =
          make_float4(e0 * inv, e1 * inv, e2 * inv, e3 * inv);
    }
  }
}

// ---------------------------------------------------------------------------
extern "C" void kernel_launch(void* const* d_in, const int* in_sizes, int n_in,
                              void* d_out, int out_size, void* d_ws, size_t ws_size,
                              hipStream_t stream) {
  const float* x  = (const float*)d_in[0];
  const float* ev = (const float*)d_in[1];
  const float* W1 = (const float*)d_in[2];
  const float* b1 = (const float*)d_in[3];
  const float* W2 = (const float*)d_in[4];
  const float* b2 = (const float*)d_in[5];
  const float* W3 = (const float*)d_in[6];
  const float* b3 = (const float*)d_in[7];
  const int* es = (const int*)d_in[8];
  const int* ed = (const int*)d_in[9];

  const int N = in_sizes[0] / D;
  const int E = in_sizes[1];

  // Workspace layout (all 16B-aligned).
  char* p = (char*)d_ws;
  unsigned int* BA = (unsigned int*)p; p += (size_t)N * 64 * sizeof(unsigned int);
  unsigned int* BB = (unsigned int*)p; p += (size_t)N * 64 * sizeof(unsigned int);
  int2* sorted = (int2*)p;          p += ((size_t)E + 7 * (size_t)N + 8) * sizeof(int2);
  int2* coarse = (int2*)p;          p += ((size_t)E + 8) * sizeof(int2);
  int* Hc = (int*)p;                p += (size_t)PBLK * NBK * sizeof(int);
  int* Btot = (int*)p;              p += (NBK + 8) * sizeof(int);
  int* Bbase = (int*)p;             p += (NBK + 8) * sizeof(int);
  int* count  = (int*)p;            p += (size_t)N * sizeof(int);
  int* rowptr = (int*)p;            p += ((size_t)N + 8) * sizeof(int);
  int* blockSums = (int*)p;         p += 1024 * sizeof(int);

  const int nblk256 = (N + 255) / 256;
  const int nblkScan = (N + SCAN_CHUNK - 1) / SCAN_CHUNK;
  const int pairgrid = ((N + 1) / 2 + 3) / 4;  // 2 rows/wave, 4 waves/block
  const int dense_grid = (N + 127) / 128;
  const int nbuckets = (N + 127) >> 7;         // <= NBK for N <= 131072
  const int chunk = (E + PBLK - 1) / PBLK;

  // --- Build padded dst-sorted CSR (zero device-scope atomics) ---
  coarse_hist<<<PBLK, 256, 0, stream>>>(ed, Hc, E, chunk);
  col_prefix<<<NBK / 256, 256, 0, stream>>>(Hc, Btot, PBLK);
  bucket_scan<<<1, 1024, 0, stream>>>(Btot, Bbase);
  coarse_scatter<<<PBLK, 256, 0, stream>>>(es, ed, ev, Hc, Bbase, coarse, E, chunk);
  fine_hist<<<nbuckets, 256, 0, stream>>>(coarse, Bbase, count, N);
  scan_blocks<<<nblkScan, 256, 0, stream>>>(count, rowptr, blockSums, N);
  scan_top<<<1, 256, 0, stream>>>(blockSums, nblkScan);
  add_offsets<<<nblk256, 256, 0, stream>>>(rowptr, blockSums, count, N);
  fine_scatter<<<nbuckets, 256, 0, stream>>>(coarse, Bbase, rowptr, sorted, N);

  // --- Layer 1: Y1 = x@W1^T (fp32 in), h1 = sigmoid(A@Y1 + b1) ---
  dense_nt<1><<<dense_grid, 512, 0, stream>>>(x, W1, (unsigned short*)BA, N);
  spmm_fused<0><<<pairgrid, 256, 0, stream>>>(BA, sorted, rowptr, b1, BB, N);
  // --- Layer 2 ---
  dense_nt<0><<<dense_grid, 512, 0, stream>>>(BB, W2, (unsigned short*)BA, N);
  spmm_fused<0><<<pairgrid, 256, 0, stream>>>(BA, sorted, rowptr, b2, BB, N);
  // --- Layer 3: Y3 = h2@W3^T, out = softmax(A@Y3 + b3) ---
  dense_nt<0><<<dense_grid, 512, 0, stream>>>(BB, W3, (unsigned short*)BA, N);
  spmm_fused<1><<<pairgrid, 256, 0, stream>>>(BA, sorted, rowptr, b3, d_out, N);
}

// Round 15
// 316.023 us; speedup vs baseline: 1.0823x; 1.0152x over previous
//
#include <hip/hip_runtime.h>
#include <hip/hip_bf16.h>
#include <cstdint>
#include <cstddef>

#define D 128
#define SCAN_CHUNK 1024

typedef __attribute__((ext_vector_type(8))) __bf16 bf16v8;
typedef __attribute__((ext_vector_type(4))) float f32v4;

// Round-to-nearest-even fp32 -> bf16 (bits), packed pair.
__device__ inline unsigned int pack_bf16x2(float a, float b) {
  unsigned int ua = __float_as_uint(a);
  unsigned int ub = __float_as_uint(b);
  ua = (ua + 0x7fffu + ((ua >> 16) & 1u)) >> 16;
  ub = (ub + 0x7fffu + ((ub >> 16) & 1u)) >> 16;
  return ua | (ub << 16);
}
__device__ inline float bf_lo(unsigned int u) { return __uint_as_float(u << 16); }
__device__ inline float bf_hi(unsigned int u) { return __uint_as_float(u & 0xffff0000u); }

// ---------------------------------------------------------------------------
// Counting-sort pipeline (round-8 measured optimum, restored): build
// dst-sorted CSR of (src<<8, val), rows PADDED to multiple of 8 with
// (0, 0.0f) fillers.  rowptr has N+1 entries; deltas ARE padded lengths.
// hist/scatter: 4 edges/thread -> 4 independent atomic chains in flight.
// (Two-level LDS sort measured R13/R14: 342/321us total — no better than
// this far-atomic form's 316us; far-atomic op throughput ~= extra passes.)
// ---------------------------------------------------------------------------
__global__ __launch_bounds__(256) void hist_kernel(
    const int* __restrict__ dst, int* __restrict__ count, int E) {
  int base = (blockIdx.x * 256 + threadIdx.x) * 4;
  if (base + 3 < E) {
    int4 d = *(const int4*)(dst + base);
    atomicAdd(&count[d.x], 1);
    atomicAdd(&count[d.y], 1);
    atomicAdd(&count[d.z], 1);
    atomicAdd(&count[d.w], 1);
  } else {
    for (int e = base; e < E; ++e) atomicAdd(&count[dst[e]], 1);
  }
}

// Scans PADDED lengths: pad8(c) = (c+7)&~7.
__global__ __launch_bounds__(256) void scan_blocks(
    const int* __restrict__ count, int* __restrict__ rowptr,
    int* __restrict__ blockSums, int n) {
  __shared__ int sdata[256];
  const int tid = threadIdx.x;
  const int base = blockIdx.x * SCAN_CHUNK;
  int v[4];
#pragma unroll
  for (int k = 0; k < 4; ++k) {
    int idx = base + tid * 4 + k;
    int c = (idx < n) ? count[idx] : 0;
    v[k] = (c + 7) & ~7;
  }
  int s = v[0] + v[1] + v[2] + v[3];
  sdata[tid] = s;
  __syncthreads();
  for (int off = 1; off < 256; off <<= 1) {
    int x = (tid >= off) ? sdata[tid - off] : 0;
    __syncthreads();
    sdata[tid] += x;
    __syncthreads();
  }
  int run = sdata[tid] - s;
#pragma unroll
  for (int k = 0; k < 4; ++k) {
    int idx = base + tid * 4 + k;
    if (idx < n) rowptr[idx] = run;
    run += v[k];
  }
  if (tid == 255) blockSums[blockIdx.x] = sdata[255];
}

__global__ __launch_bounds__(256) void scan_top(int* __restrict__ bs, int nblk) {
  __shared__ int sdata[256];
  const int tid = threadIdx.x;
  int v[4];
#pragma unroll
  for (int k = 0; k < 4; ++k) {
    int idx = tid * 4 + k;
    v[k] = (idx < nblk) ? bs[idx] : 0;
  }
  int s = v[0] + v[1] + v[2] + v[3];
  sdata[tid] = s;
  __syncthreads();
  for (int off = 1; off < 256; off <<= 1) {
    int x = (tid >= off) ? sdata[tid - off] : 0;
    __syncthreads();
    sdata[tid] += x;
    __syncthreads();
  }
  int run = sdata[tid] - s;
#pragma unroll
  for (int k = 0; k < 4; ++k) {
    int idx = tid * 4 + k;
    if (idx < nblk) { int t = v[k]; bs[idx] = run; run += t; }
  }
}

// Finalize rowptr/cursor, zero-fill each row's padding slots, and write the
// rowptr[n] terminator.
__global__ __launch_bounds__(256) void add_offsets(
    int* __restrict__ rowptr, int* __restrict__ cursor,
    const int* __restrict__ bs, const int* __restrict__ count,
    int2* __restrict__ sorted, int n) {
  int i = blockIdx.x * 256 + threadIdx.x;
  if (i < n) {
    int v = rowptr[i] + bs[i >> 10];
    rowptr[i] = v;
    cursor[i] = v;
    int c = count[i];
    int lp = (c + 7) & ~7;
    for (int k = c; k < lp; ++k) sorted[v + k] = make_int2(0, 0);
    if (i == n - 1) rowptr[n] = v + lp;
  }
}

// Records store src pre-scaled to a byte offset (src * 256).
// 4 edges/thread: 4 independent atomic->store chains overlap.
__global__ __launch_bounds__(256) void scatter_edges(
    const int* __restrict__ src, const int* __restrict__ dst,
    const float* __restrict__ val, int* __restrict__ cursor,
    int2* __restrict__ sorted, int E) {
  int base = (blockIdx.x * 256 + threadIdx.x) * 4;
  if (base + 3 < E) {
    int4 s4 = *(const int4*)(src + base);
    int4 d4 = *(const int4*)(dst + base);
    float4 v4 = *(const float4*)(val + base);
    int p0 = atomicAdd(&cursor[d4.x], 1);
    int p1 = atomicAdd(&cursor[d4.y], 1);
    int p2 = atomicAdd(&cursor[d4.z], 1);
    int p3 = atomicAdd(&cursor[d4.w], 1);
    sorted[p0] = make_int2(s4.x << 8, __float_as_int(v4.x));
    sorted[p1] = make_int2(s4.y << 8, __float_as_int(v4.y));
    sorted[p2] = make_int2(s4.z << 8, __float_as_int(v4.z));
    sorted[p3] = make_int2(s4.w << 8, __float_as_int(v4.w));
  } else {
    for (int e = base; e < E; ++e) {
      int t = dst[e];
      int pos = atomicAdd(&cursor[t], 1);
      sorted[pos] = make_int2(src[e] << 8, __float_as_int(val[e]));
    }
  }
}

// ---------------------------------------------------------------------------
// Weight cast: W (3 matrices, fp32 128x128) -> bf16, once per call.
// ---------------------------------------------------------------------------
__global__ __launch_bounds__(256) void cast_w(
    const float* __restrict__ W1, const float* __restrict__ W2,
    const float* __restrict__ W3, unsigned short* __restrict__ out) {
  const float* src[3] = {W1, W2, W3};
  int m = blockIdx.y;
  int i = blockIdx.x * 256 + threadIdx.x;
  if (i < D * D) {
    unsigned int u = __float_as_uint(src[m][i]);
    out[(size_t)m * D * D + i] =
        (unsigned short)((u + 0x7fffu + ((u >> 16) & 1u)) >> 16);
  }
}

// ---------------------------------------------------------------------------
// Dense transform Y = in @ W^T (round-8 measured optimum): operand-swapped
// MFMA (A=W frag, B=H frag -> lane holds Y[row][4 consecutive cols] -> 8 x
// 8B uint2 stores per lane), coalesced LDS staging for H and W, 512-thread
// blocks (16 waves/CU at the 2-block LDS limit).
// ---------------------------------------------------------------------------
template <int F32IN>
__global__ __launch_bounds__(512) void dense_nt(
    const void* __restrict__ in_v, const unsigned short* __restrict__ Wb,
    unsigned short* __restrict__ out, int M) {
  __shared__ __align__(16) unsigned short Hs[128 * 136];
  __shared__ __align__(16) unsigned short Ws[128 * 136];

  const int tid = threadIdx.x;          // 0..511
  const int w = tid >> 6;               // 0..7
  const int lane = tid & 63;
  const int lane15 = lane & 15;
  const int quad = lane >> 4;
  const int row0 = blockIdx.x * 128;

  // --- Stage W (coalesced): 2048 x uint4, 4 per thread ---
  const uint4* w16 = (const uint4*)Wb;
#pragma unroll
  for (int it = 0; it < 4; ++it) {
    int c = it * 512 + tid;  // 0..2047
    int r = c >> 4;
    int ck = c & 15;
    *(uint4*)&Ws[r * 136 + ck * 8] = w16[(size_t)r * 16 + ck];
  }

  // --- Stage H (coalesced) ---
  if (F32IN) {
    const float4* in32 = (const float4*)in_v;  // 32 chunks of 4 floats per row
#pragma unroll
    for (int it = 0; it < 8; ++it) {
      int c = it * 512 + tid;  // 0..4095
      int r = c >> 5;
      int ck = c & 31;
      float4 g = make_float4(0.f, 0.f, 0.f, 0.f);
      if (row0 + r < M) g = in32[(size_t)(row0 + r) * 32 + ck];
      uint2 pk = make_uint2(pack_bf16x2(g.x, g.y), pack_bf16x2(g.z, g.w));
      *(uint2*)&Hs[r * 136 + ck * 4] = pk;
    }
  } else {
    const uint4* in16 = (const uint4*)in_v;  // 16 chunks per bf16 row
#pragma unroll
    for (int it = 0; it < 4; ++it) {
      int c = it * 512 + tid;  // 0..2047
      int r = c >> 4;
      int ck = c & 15;
      uint4 g = make_uint4(0, 0, 0, 0);
      if (row0 + r < M) g = in16[(size_t)(row0 + r) * 16 + ck];
      *(uint4*)&Hs[r * 136 + ck * 8] = g;
    }
  }
  __syncthreads();

  // Wave w owns output rows m = row0 + w*16 + lane15.
  const int mrow = row0 + w * 16 + lane15;
  bf16v8 hf[4];
#pragma unroll
  for (int kt = 0; kt < 4; ++kt)
    hf[kt] = *(const bf16v8*)&Hs[(w * 16 + lane15) * 136 + kt * 32 + quad * 8];

  f32v4 acc[8];
#pragma unroll
  for (int nt = 0; nt < 8; ++nt) acc[nt] = (f32v4){0.f, 0.f, 0.f, 0.f};

#pragma unroll
  for (int kt = 0; kt < 4; ++kt) {
    const int ko = kt * 32 + quad * 8;
#pragma unroll
    for (int nt = 0; nt < 8; ++nt) {
      bf16v8 a = *(const bf16v8*)&Ws[(nt * 16 + lane15) * 136 + ko];
      acc[nt] = __builtin_amdgcn_mfma_f32_16x16x32_bf16(a, hf[kt], acc[nt], 0, 0, 0);
    }
  }

  // --- Epilogue: lane holds Y[mrow][nt*16 + quad*4 + r], r=0..3 ---
  if (mrow < M) {
#pragma unroll
    for (int nt = 0; nt < 8; ++nt) {
      uint2 pk;
      pk.x = pack_bf16x2(acc[nt][0], acc[nt][1]);
      pk.y = pack_bf16x2(acc[nt][2], acc[nt][3]);
      *(uint2*)&out[(size_t)mrow * D + nt * 16 + quad * 4] = pk;
    }
  }
}

// ---------------------------------------------------------------------------
// Fused SpMM (round-11 form, the measured optimum of the ILP family:
// 1 row = 61us latency-bound, 2 rows = 37us, 4 rows = 40us+).
// TWO rows per wave, processed concurrently: one scalar fetch covers both
// rowptr spans; both rows' record loads and gathers in flight together
// (8 outstanding gathers/wave).  2 edge-parity groups x 32 lanes; lane l
// owns dims 4l..4l+3; uint2 gathers (one instr = 2 rows x 256B); padded
// rows keep the loop branch-free.  Epilogue parallel: half g=0 finalizes
// rowA while g=1 does rowB.
// MODE 0: bias+sigmoid -> bf16.  MODE 1: bias+row-softmax -> fp32.
// ---------------------------------------------------------------------------
template <int MODE>
__global__ __launch_bounds__(256) void spmm_fused(
    const unsigned int* __restrict__ h, const int2* __restrict__ sorted,
    const int* __restrict__ rowptr,
    const float* __restrict__ bias, void* __restrict__ out_v, int n) {
  const int wave = threadIdx.x >> 6;
  const int lane = threadIdx.x & 63;
  const int g = lane >> 5;   // parity group / epilogue row select
  const int l = lane & 31;   // dim chunk: owns dims 4l..4l+3
  int pairid = blockIdx.x * 4 + wave;
  int rowA = __builtin_amdgcn_readfirstlane(pairid * 2);
  if (rowA >= n) return;
  const int rowB = rowA + 1;
  const bool hasB = rowB < n;
  const int sA = __builtin_amdgcn_readfirstlane(rowptr[rowA]);
  const int eA = __builtin_amdgcn_readfirstlane(rowptr[rowA + 1]);
  const int eB = hasB ? __builtin_amdgcn_readfirstlane(rowptr[rowA + 2]) : eA;
  const int lpA = eA - sA;
  const int lpB = eB - eA;

  const char* hb = (const char*)h;
  const char* sb = (const char*)sorted;
  const unsigned lb = (unsigned)l << 3;
  unsigned soA = (unsigned)sA << 3;
  unsigned soB = (unsigned)eA << 3;

  float4 bb = ((const float4*)bias)[l];  // hoisted; overlaps edge walk

  float a0 = 0.f, a1 = 0.f, a2 = 0.f, a3 = 0.f;   // rowA
  float b0 = 0.f, b1 = 0.f, b2 = 0.f, b3 = 0.f;   // rowB

  const int m = (lpA < lpB) ? lpA : lpB;
  int j = 0;
  // --- joint loop: both rows' batches in flight together ---
  for (; j < m; j += 8, soA += 64, soB += 64) {
    int4 pa0 = *(const int4*)(sb + soA);
    int4 pa1 = *(const int4*)(sb + soA + 16);
    int4 pa2 = *(const int4*)(sb + soA + 32);
    int4 pa3 = *(const int4*)(sb + soA + 48);
    int4 pb0 = *(const int4*)(sb + soB);
    int4 pb1 = *(const int4*)(sb + soB + 16);
    int4 pb2 = *(const int4*)(sb + soB + 32);
    int4 pb3 = *(const int4*)(sb + soB + 48);
    unsigned ba0 = (unsigned)(g ? pa0.z : pa0.x);
    unsigned ba1 = (unsigned)(g ? pa1.z : pa1.x);
    unsigned ba2 = (unsigned)(g ? pa2.z : pa2.x);
    unsigned ba3 = (unsigned)(g ? pa3.z : pa3.x);
    unsigned bb0 = (unsigned)(g ? pb0.z : pb0.x);
    unsigned bb1 = (unsigned)(g ? pb1.z : pb1.x);
    unsigned bb2 = (unsigned)(g ? pb2.z : pb2.x);
    unsigned bb3 = (unsigned)(g ? pb3.z : pb3.x);
    uint2 ua0 = *(const uint2*)(hb + (ba0 + lb));
    uint2 ua1 = *(const uint2*)(hb + (ba1 + lb));
    uint2 ua2 = *(const uint2*)(hb + (ba2 + lb));
    uint2 ua3 = *(const uint2*)(hb + (ba3 + lb));
    uint2 ub0 = *(const uint2*)(hb + (bb0 + lb));
    uint2 ub1 = *(const uint2*)(hb + (bb1 + lb));
    uint2 ub2 = *(const uint2*)(hb + (bb2 + lb));
    uint2 ub3 = *(const uint2*)(hb + (bb3 + lb));
    float va0 = __int_as_float(g ? pa0.w : pa0.y);
    float va1 = __int_as_float(g ? pa1.w : pa1.y);
    float va2 = __int_as_float(g ? pa2.w : pa2.y);
    float va3 = __int_as_float(g ? pa3.w : pa3.y);
    float vb0 = __int_as_float(g ? pb0.w : pb0.y);
    float vb1 = __int_as_float(g ? pb1.w : pb1.y);
    float vb2 = __int_as_float(g ? pb2.w : pb2.y);
    float vb3 = __int_as_float(g ? pb3.w : pb3.y);
    a0 = fmaf(va0, bf_lo(ua0.x), a0); a1 = fmaf(va0, bf_hi(ua0.x), a1);
    a2 = fmaf(va0, bf_lo(ua0.y), a2); a3 = fmaf(va0, bf_hi(ua0.y), a3);
    a0 = fmaf(va1, bf_lo(ua1.x), a0); a1 = fmaf(va1, bf_hi(ua1.x), a1);
    a2 = fmaf(va1, bf_lo(ua1.y), a2); a3 = fmaf(va1, bf_hi(ua1.y), a3);
    a0 = fmaf(va2, bf_lo(ua2.x), a0); a1 = fmaf(va2, bf_hi(ua2.x), a1);
    a2 = fmaf(va2, bf_lo(ua2.y), a2); a3 = fmaf(va2, bf_hi(ua2.y), a3);
    a0 = fmaf(va3, bf_lo(ua3.x), a0); a1 = fmaf(va3, bf_hi(ua3.x), a1);
    a2 = fmaf(va3, bf_lo(ua3.y), a2); a3 = fmaf(va3, bf_hi(ua3.y), a3);
    b0 = fmaf(vb0, bf_lo(ub0.x), b0); b1 = fmaf(vb0, bf_hi(ub0.x), b1);
    b2 = fmaf(vb0, bf_lo(ub0.y), b2); b3 = fmaf(vb0, bf_hi(ub0.y), b3);
    b0 = fmaf(vb1, bf_lo(ub1.x), b0); b1 = fmaf(vb1, bf_hi(ub1.x), b1);
    b2 = fmaf(vb1, bf_lo(ub1.y), b2); b3 = fmaf(vb1, bf_hi(ub1.y), b3);
    b0 = fmaf(vb2, bf_lo(ub2.x), b0); b1 = fmaf(vb2, bf_hi(ub2.x), b1);
    b2 = fmaf(vb2, bf_lo(ub2.y), b2); b3 = fmaf(vb2, bf_hi(ub2.y), b3);
    b0 = fmaf(vb3, bf_lo(ub3.x), b0); b1 = fmaf(vb3, bf_hi(ub3.x), b1);
    b2 = fmaf(vb3, bf_lo(ub3.y), b2); b3 = fmaf(vb3, bf_hi(ub3.y), b3);
  }
  // --- rowA tail (lpA > m) ---
  for (int ja = j; ja < lpA; ja += 8, soA += 64) {
    int4 p0 = *(const int4*)(sb + soA);
    int4 p1 = *(const int4*)(sb + soA + 16);
    int4 p2 = *(const int4*)(sb + soA + 32);
    int4 p3 = *(const int4*)(sb + soA + 48);
    unsigned c0 = (unsigned)(g ? p0.z : p0.x);
    unsigned c1 = (unsigned)(g ? p1.z : p1.x);
    unsigned c2 = (unsigned)(g ? p2.z : p2.x);
    unsigned c3 = (unsigned)(g ? p3.z : p3.x);
    uint2 u0 = *(const uint2*)(hb + (c0 + lb));
    uint2 u1 = *(const uint2*)(hb + (c1 + lb));
    uint2 u2 = *(const uint2*)(hb + (c2 + lb));
    uint2 u3 = *(const uint2*)(hb + (c3 + lb));
    float v0 = __int_as_float(g ? p0.w : p0.y);
    float v1 = __int_as_float(g ? p1.w : p1.y);
    float v2 = __int_as_float(g ? p2.w : p2.y);
    float v3 = __int_as_float(g ? p3.w : p3.y);
    a0 = fmaf(v0, bf_lo(u0.x), a0); a1 = fmaf(v0, bf_hi(u0.x), a1);
    a2 = fmaf(v0, bf_lo(u0.y), a2); a3 = fmaf(v0, bf_hi(u0.y), a3);
    a0 = fmaf(v1, bf_lo(u1.x), a0); a1 = fmaf(v1, bf_hi(u1.x), a1);
    a2 = fmaf(v1, bf_lo(u1.y), a2); a3 = fmaf(v1, bf_hi(u1.y), a3);
    a0 = fmaf(v2, bf_lo(u2.x), a0); a1 = fmaf(v2, bf_hi(u2.x), a1);
    a2 = fmaf(v2, bf_lo(u2.y), a2); a3 = fmaf(v2, bf_hi(u2.y), a3);
    a0 = fmaf(v3, bf_lo(u3.x), a0); a1 = fmaf(v3, bf_hi(u3.x), a1);
    a2 = fmaf(v3, bf_lo(u3.y), a2); a3 = fmaf(v3, bf_hi(u3.y), a3);
  }
  // --- rowB tail (lpB > m) ---
  for (int jb = j; jb < lpB; jb += 8, soB += 64) {
    int4 p0 = *(const int4*)(sb + soB);
    int4 p1 = *(const int4*)(sb + soB + 16);
    int4 p2 = *(const int4*)(sb + soB + 32);
    int4 p3 = *(const int4*)(sb + soB + 48);
    unsigned c0 = (unsigned)(g ? p0.z : p0.x);
    unsigned c1 = (unsigned)(g ? p1.z : p1.x);
    unsigned c2 = (unsigned)(g ? p2.z : p2.x);
    unsigned c3 = (unsigned)(g ? p3.z : p3.x);
    uint2 u0 = *(const uint2*)(hb + (c0 + lb));
    uint2 u1 = *(const uint2*)(hb + (c1 + lb));
    uint2 u2 = *(const uint2*)(hb + (c2 + lb));
    uint2 u3 = *(const uint2*)(hb + (c3 + lb));
    float v0 = __int_as_float(g ? p0.w : p0.y);
    float v1 = __int_as_float(g ? p1.w : p1.y);
    float v2 = __int_as_float(g ? p2.w : p2.y);
    float v3 = __int_as_float(g ? p3.w : p3.y);
    b0 = fmaf(v0, bf_lo(u0.x), b0); b1 = fmaf(v0, bf_hi(u0.x), b1);
    b2 = fmaf(v0, bf_lo(u0.y), b2); b3 = fmaf(v0, bf_hi(u0.y), b3);
    b0 = fmaf(v1, bf_lo(u1.x), b0); b1 = fmaf(v1, bf_hi(u1.x), b1);
    b2 = fmaf(v1, bf_lo(u1.y), b2); b3 = fmaf(v1, bf_hi(u1.y), b3);
    b0 = fmaf(v2, bf_lo(u2.x), b0); b1 = fmaf(v2, bf_hi(u2.x), b1);
    b2 = fmaf(v2, bf_lo(u2.y), b2); b3 = fmaf(v2, bf_hi(u2.y), b3);
    b0 = fmaf(v3, bf_lo(u3.x), b0); b1 = fmaf(v3, bf_hi(u3.x), b1);
    b2 = fmaf(v3, bf_lo(u3.y), b2); b3 = fmaf(v3, bf_hi(u3.y), b3);
  }

  // Cross-parity merge: afterwards BOTH halves hold each row's full sums.
  a0 += __shfl_xor(a0, 32); a1 += __shfl_xor(a1, 32);
  a2 += __shfl_xor(a2, 32); a3 += __shfl_xor(a3, 32);
  b0 += __shfl_xor(b0, 32); b1 += __shfl_xor(b1, 32);
  b2 += __shfl_xor(b2, 32); b3 += __shfl_xor(b3, 32);

  // Half g finalizes row (g ? rowB : rowA).
  float r0 = (g ? b0 : a0) + bb.x;
  float r1 = (g ? b1 : a1) + bb.y;
  float r2 = (g ? b2 : a2) + bb.z;
  float r3 = (g ? b3 : a3) + bb.w;
  const int row = g ? rowB : rowA;
  const bool doStore = (g == 0) || hasB;

  if (MODE == 0) {
    if (doStore) {
      uint2 pk;
      pk.x = pack_bf16x2(1.0f / (1.0f + __expf(-r0)), 1.0f / (1.0f + __expf(-r1)));
      pk.y = pack_bf16x2(1.0f / (1.0f + __expf(-r2)), 1.0f / (1.0f + __expf(-r3)));
      ((uint2*)out_v)[(size_t)row * 32 + l] = pk;
    }
  } else {
    // Per-half softmax over the 32 lanes of this half (offsets < 32 stay
    // within the half).
    float mx = fmaxf(fmaxf(r0, r1), fmaxf(r2, r3));
#pragma unroll
    for (int off = 16; off; off >>= 1) mx = fmaxf(mx, __shfl_xor(mx, off));
    float e0 = __expf(r0 - mx), e1 = __expf(r1 - mx);
    float e2 = __expf(r2 - mx), e3 = __expf(r3 - mx);
    float s = (e0 + e1) + (e2 + e3);
#pragma unroll
    for (int off = 16; off; off >>= 1) s += __shfl_xor(s, off);
    float inv = 1.0f / s;
    if (doStore) {
      ((float4*)out_v)[(size_t)row * 32 + l] =
          make_float4(e0 * inv, e1 * inv, e2 * inv, e3 * inv);
    }
  }
}

// ---------------------------------------------------------------------------
extern "C" void kernel_launch(void* const* d_in, const int* in_sizes, int n_in,
                              void* d_out, int out_size, void* d_ws, size_t ws_size,
                              hipStream_t stream) {
  const float* x  = (const float*)d_in[0];
  const float* ev = (const float*)d_in[1];
  const float* W1 = (const float*)d_in[2];
  const float* b1 = (const float*)d_in[3];
  const float* W2 = (const float*)d_in[4];
  const float* b2 = (const float*)d_in[5];
  const float* W3 = (const float*)d_in[6];
  const float* b3 = (const float*)d_in[7];
  const int* es = (const int*)d_in[8];
  const int* ed = (const int*)d_in[9];

  const int N = in_sizes[0] / D;
  const int E = in_sizes[1];

  // Workspace layout (all 16B-aligned).  sorted holds up to E + 7N records
  // (worst-case pad8 expansion); rowptr has N+1 entries (+pad).
  char* p = (char*)d_ws;
  unsigned int* BA = (unsigned int*)p; p += (size_t)N * 64 * sizeof(unsigned int);
  unsigned int* BB = (unsigned int*)p; p += (size_t)N * 64 * sizeof(unsigned int);
  int2* sorted = (int2*)p;          p += ((size_t)E + 7 * (size_t)N + 8) * sizeof(int2);
  unsigned short* Wb = (unsigned short*)p; p += 3 * (size_t)D * D * sizeof(unsigned short);
  int* count  = (int*)p;            p += (size_t)N * sizeof(int);
  int* rowptr = (int*)p;            p += ((size_t)N + 8) * sizeof(int);
  int* cursor = (int*)p;            p += (size_t)N * sizeof(int);
  int* blockSums = (int*)p;         p += 1024 * sizeof(int);

  const int eblk4 = (E + 1023) / 1024;   // 4 edges/thread
  const int nblk256 = (N + 255) / 256;
  const int nblkScan = (N + SCAN_CHUNK - 1) / SCAN_CHUNK;
  const int pairgrid = ((N + 1) / 2 + 3) / 4;  // 2 rows/wave, 4 waves/block
  const int dense_grid = (N + 127) / 128;

  // --- Build padded dst-sorted CSR + bf16 weights ---
  (void)hipMemsetAsync(count, 0, (size_t)N * sizeof(int), stream);
  hist_kernel<<<eblk4, 256, 0, stream>>>(ed, count, E);
  cast_w<<<dim3((D * D + 255) / 256, 3), 256, 0, stream>>>(W1, W2, W3, Wb);
  scan_blocks<<<nblkScan, 256, 0, stream>>>(count, rowptr, blockSums, N);
  scan_top<<<1, 256, 0, stream>>>(blockSums, nblkScan);
  add_offsets<<<nblk256, 256, 0, stream>>>(rowptr, cursor, blockSums, count, sorted, N);
  scatter_edges<<<eblk4, 256, 0, stream>>>(es, ed, ev, cursor, sorted, E);

  // --- Layer 1: Y1 = x@W1^T (fp32 in), h1 = sigmoid(A@Y1 + b1) ---
  dense_nt<1><<<dense_grid, 512, 0, stream>>>(x, Wb + 0 * D * D,
                                              (unsigned short*)BA, N);
  spmm_fused<0><<<pairgrid, 256, 0, stream>>>(BA, sorted, rowptr, b1, BB, N);
  // --- Layer 2 ---
  dense_nt<0><<<dense_grid, 512, 0, stream>>>(BB, Wb + 1 * D * D,
                                              (unsigned short*)BA, N);
  spmm_fused<0><<<pairgrid, 256, 0, stream>>>(BA, sorted, rowptr, b2, BB, N);
  // --- Layer 3: Y3 = h2@W3^T, out = softmax(A@Y3 + b3) ---
  dense_nt<0><<<dense_grid, 512, 0, stream>>>(BB, Wb + 2 * D * D,
                                              (unsigned short*)BA, N);
  spmm_fused<1><<<pairgrid, 256, 0, stream>>>(BA, sorted, rowptr, b3, d_out, N);
}